// Round 2
// baseline (415.317 us; speedup 1.0000x reference)
//
#include <hip/hip_runtime.h>

typedef float f32x4 __attribute__((ext_vector_type(4)));
typedef short s16x8 __attribute__((ext_vector_type(8)));
typedef short s16x4 __attribute__((ext_vector_type(4)));

#define NLAB 10
#define LEGO 128
#define INA  128
#define OUTC 512
#define KDIM 1152               // 9 offsets * 128 ic
#define WPITCH 34
#define XROW (WPITCH * 128)     // shorts per padded x row = 4352 (8704 B)
#define XL_ELEMS (6 * XROW)     // 26112 bf16 = 52224 B

__device__ __forceinline__ unsigned short f2bf(float f) {
    unsigned u = __builtin_bit_cast(unsigned, f);
    u += 0x7fffu + ((u >> 16) & 1u);          // round-to-nearest-even
    return (unsigned short)(u >> 16);
}
__device__ __forceinline__ float bf2f(unsigned short h) {
    return __builtin_bit_cast(float, ((unsigned)h) << 16);
}

// async 16B global->LDS DMA: lane's 16B goes to ldsbase + lane*16
__device__ __forceinline__ void g2l16(const void* g, void* l) {
    __builtin_amdgcn_global_load_lds(
        (const __attribute__((address_space(1))) void*)g,
        (__attribute__((address_space(3))) void*)l, 16, 0, 0);
}

// ---------------- shared prep pieces (both paths) --------------------------
__global__ void k_prep_w(const float* __restrict__ ff, unsigned short* __restrict__ wt) {
    int t = blockIdx.x * 256 + threadIdx.x;
    if (t >= NLAB * LEGO * INA) return;
    int ic = t & 127;
    int ll = t >> 7;                           // lab*128 + l
    const float* src = ff + (size_t)(ll * 128 + ic) * 9;
    unsigned short* dst = wt + (size_t)ll * KDIM + ic;
#pragma unroll
    for (int off = 0; off < 9; ++off) dst[off * 128] = f2bf(src[off]);
}

__global__ void k_prep_sel(const float* __restrict__ coeff, const float* __restrict__ comb,
                           int* __restrict__ sel, float* __restrict__ cs) {
    int o = blockIdx.x * 256 + threadIdx.x;
    if (o >= OUTC) return;
    const float* row = comb + (size_t)o * LEGO;
    float best = row[0]; int bi = 0;
    for (int l = 1; l < LEGO; ++l) { float v = row[l]; if (v > best) { best = v; bi = l; } }
    sel[o] = bi;
    cs[o] = coeff[(size_t)o * LEGO + bi];
}

// xbf[b][r][w1][ic'] = bf16(x) in the exact swizzled LDS-image layout;
// rows r=0 (h=-1), r=33 (h=32) and cols w1=0,33 are true zeros.
__global__ __launch_bounds__(256, 4) void k_prep_x(
    const float* __restrict__ x, unsigned short* __restrict__ xbf)
{
    const int r = blockIdx.x, b = blockIdx.y, t = threadIdx.x;
    unsigned short* dst = xbf + ((size_t)b * 34 + r) * XROW;
    if (r == 0 || r == 33) {                  // halo rows: pure zeros
        uint4* z = (uint4*)dst;
        for (int i = t; i < XROW / 8; i += 256) z[i] = make_uint4(0u,0u,0u,0u);
        return;
    }
    __shared__ float sx[128][33];             // +1 pad: conflict-free column reads
    const int h = r - 1;
    for (int c = t; c < 1024; c += 256) {     // coalesced f32x4 loads of x[b][ic][h][:]
        int ic = c >> 3, wq = c & 7;
        f32x4 v = *(const f32x4*)(x + (((size_t)b * INA + ic) << 10) + h * 32 + wq * 4);
#pragma unroll
        for (int j = 0; j < 4; ++j) sx[ic][wq * 4 + j] = v[j];
    }
    __syncthreads();
    // transpose + convert + 16B-chunk XOR swizzle; fully coalesced 16B stores
    for (int task = t; task < 512; task += 256) {
        int w1 = (task >> 4) + 1;             // 1..32
        int g  = task & 15;                   // dest 16B chunk
        int sg = g ^ (w1 & 15);               // source ich
        int w  = w1 - 1;
        s16x8 o;
#pragma unroll
        for (int k = 0; k < 8; ++k) o[k] = (short)f2bf(sx[sg * 8 + k][w]);
        *(s16x8*)(dst + (w1 << 7) + (g << 3)) = o;
    }
    if (t < 32) {                             // border cols w1=0,33: zeros
        int w1 = (t & 1) ? 33 : 0;
        int g  = t >> 1;
        s16x8 zz = {0,0,0,0,0,0,0,0};
        *(s16x8*)(dst + (w1 << 7) + (g << 3)) = zz;
    }
}

// ---------------- path A: DMA-staged conv (needs 41 MB workspace) ----------
__global__ __launch_bounds__(256, 3) void k_conv_dma(
    const unsigned short* __restrict__ xbf, const int* __restrict__ label,
    const unsigned short* __restrict__ wt,
    const int* __restrict__ sel, const float* __restrict__ cs,
    float* __restrict__ out)
{
    __shared__ unsigned short xl[XL_ELEMS];   // staged x (swizzled); later aliased as feat bf16 [128][132]

    const int t  = threadIdx.x;
    const int b  = blockIdx.y;
    const int nt = blockIdx.x;                // 0..7 -> pixel rows h0..h0+3
    const int lane = t & 63;
    const int wv   = t >> 6;

    // stage: 6 padded rows = one contiguous 52224 B range; pure DMA, no VALU.
    const unsigned short* src = xbf + ((size_t)b * 34 + nt * 4) * XROW;
    for (int c = wv; c < 51; c += 4)
        g2l16(src + (c << 9) + (lane << 3), xl + (c << 9));

    const int lab = label[b];
    const int l16  = lane & 15;
    const int quad = lane >> 4;
    const int m_base = (wv & 1) << 6;
    const int n_base = (wv >> 1) << 6;

    const unsigned short* wl = wt + (size_t)lab * (LEGO * KDIM);
    const unsigned short* arow[4];
#pragma unroll
    for (int mi = 0; mi < 4; ++mi)
        arow[mi] = wl + (size_t)(m_base + mi*16 + l16) * KDIM + quad * 8;

    int prow[4], pcol[4];
#pragma unroll
    for (int ni = 0; ni < 4; ++ni) {
        int p = n_base + ni*16 + l16;
        prow[ni] = p >> 5;
        pcol[ni] = p & 31;
    }

    f32x4 acc[4][4];
    {
        f32x4 zz = {0.f, 0.f, 0.f, 0.f};
#pragma unroll
        for (int mi = 0; mi < 4; ++mi)
#pragma unroll
            for (int ni = 0; ni < 4; ++ni) acc[mi][ni] = zz;
    }

    // preload A ring for steps 0,1 (global, independent of LDS staging -> overlaps DMA)
    s16x8 ap[3][4];
#pragma unroll
    for (int s = 0; s < 2; ++s)
#pragma unroll
        for (int mi = 0; mi < 4; ++mi)
            ap[s][mi] = *(const s16x8*)(arow[mi] + s * 32);

    __syncthreads();                          // drains vmcnt: staged x + A prefetch ready

#pragma unroll
    for (int off = 0; off < 9; ++off) {
        const int dh = off / 3 - 1;
        const int dw = off % 3 - 1;
        int bbase[4], bsw[4];
#pragma unroll
        for (int ni = 0; ni < 4; ++ni) {
            int row = prow[ni] + dh + 1;      // 0..5, always staged
            int w1  = pcol[ni] + dw + 1;      // 0..33, borders are zeros
            bbase[ni] = (row * WPITCH + w1) * 128;
            bsw[ni]   = w1 & 15;
        }
#pragma unroll
        for (int kc = 0; kc < 4; ++kc) {
            const int step = off * 4 + kc;
            if (step + 2 < 36) {              // prefetch A for step+2
#pragma unroll
                for (int mi = 0; mi < 4; ++mi)
                    ap[(step + 2) % 3][mi] = *(const s16x8*)(arow[mi] + (step + 2) * 32);
            }
            const int jj = kc * 4 + quad;
            s16x8 bb[4];
#pragma unroll
            for (int ni = 0; ni < 4; ++ni)
                bb[ni] = *(const s16x8*)(xl + bbase[ni] + ((jj ^ bsw[ni]) << 3)); // ds_read_b128
            const s16x8* a = ap[step % 3];
#pragma unroll
            for (int mi = 0; mi < 4; ++mi)
#pragma unroll
                for (int ni = 0; ni < 4; ++ni)
                    acc[mi][ni] = __builtin_amdgcn_mfma_f32_16x16x32_bf16(a[mi], bb[ni], acc[mi][ni], 0, 0, 0);
        }
    }

    __syncthreads();                          // all LDS x reads done; reuse as feat
    unsigned short* featb = xl;               // feat bf16 [128][132] (pad breaks quad collisions)
#pragma unroll
    for (int mi = 0; mi < 4; ++mi)
#pragma unroll
        for (int ni = 0; ni < 4; ++ni) {
            int n = n_base + ni*16 + l16;
#pragma unroll
            for (int r = 0; r < 4; ++r) {
                int m = m_base + mi*16 + quad*4 + r;   // m89-verified C/D layout
                featb[m * 132 + n] = f2bf(acc[mi][ni][r]);
            }
        }
    __syncthreads();

    const size_t obase = ((size_t)b * OUTC) * 1024 + (size_t)nt * 128;
    for (int i = t; i < OUTC * 32; i += 256) {
        int pg = i & 31;
        int o  = i >> 5;
        int so = sel[o];
        float cc = cs[o];
        s16x4 fv = *(const s16x4*)(featb + so * 132 + pg * 4);
        f32x4 ov;
#pragma unroll
        for (int j = 0; j < 4; ++j)
            ov[j] = cc * bf2f((unsigned short)fv[j]);
        __builtin_nontemporal_store(ov, (f32x4*)(out + obase + (size_t)o * 1024 + pg * 4));
    }
}

// ---------------- path B: verified fallback (in-kernel staging, 412 µs) ----
__global__ __launch_bounds__(256, 2) void k_conv_old(
    const float* __restrict__ x, const int* __restrict__ label,
    const unsigned short* __restrict__ wt,
    const int* __restrict__ sel, const float* __restrict__ cs,
    float* __restrict__ out)
{
    __shared__ unsigned short xl[XL_ELEMS];

    const int t  = threadIdx.x;
    const int b  = blockIdx.y;
    const int nt = blockIdx.x;
    const int h0 = nt * 4;

    {
        uint4* z = (uint4*)xl;
        for (int i = t; i < XL_ELEMS/8; i += 256) z[i] = make_uint4(0u,0u,0u,0u);
    }
    __syncthreads();

    const int lab = label[b];

    for (int i = t; i < 6144; i += 256) {
        int wq  = i & 7;
        int ri  = i >> 3;
        int row = ri % 6;
        int ic  = ri / 6;
        int h = h0 - 1 + row;
        if (h >= 0 && h < 32) {
            const f32x4 v = *(const f32x4*)(x + (((size_t)b * INA + ic) << 10) + h * 32 + wq * 4);
            int icl = ic & 7, ich = ic >> 3;
#pragma unroll
            for (int j = 0; j < 4; ++j) {
                int w1 = wq * 4 + j + 1;
                int el = (row * WPITCH + w1) * 128 + (((ich ^ (w1 & 15)) << 3) | icl);
                xl[el] = f2bf(v[j]);
            }
        }
    }
    __syncthreads();

    const int lane = t & 63;
    const int wv   = t >> 6;
    const int l16  = lane & 15;
    const int quad = lane >> 4;
    const int m_base = (wv & 1) << 6;
    const int n_base = (wv >> 1) << 6;

    const unsigned short* wl = wt + (size_t)lab * (LEGO * KDIM);
    const unsigned short* arow[4];
#pragma unroll
    for (int mi = 0; mi < 4; ++mi)
        arow[mi] = wl + (size_t)(m_base + mi*16 + l16) * KDIM + quad * 8;

    int prow[4], pcol[4];
#pragma unroll
    for (int ni = 0; ni < 4; ++ni) {
        int p = n_base + ni*16 + l16;
        prow[ni] = p >> 5;
        pcol[ni] = p & 31;
    }

    f32x4 acc[4][4];
    {
        f32x4 zz = {0.f, 0.f, 0.f, 0.f};
#pragma unroll
        for (int mi = 0; mi < 4; ++mi)
#pragma unroll
            for (int ni = 0; ni < 4; ++ni) acc[mi][ni] = zz;
    }

    s16x8 ap[3][4];
#pragma unroll
    for (int s = 0; s < 2; ++s)
#pragma unroll
        for (int mi = 0; mi < 4; ++mi)
            ap[s][mi] = *(const s16x8*)(arow[mi] + s * 32);

#pragma unroll
    for (int off = 0; off < 9; ++off) {
        const int dh = off / 3 - 1;
        const int dw = off % 3 - 1;
        int bbase[4], bsw[4];
#pragma unroll
        for (int ni = 0; ni < 4; ++ni) {
            int row = prow[ni] + dh + 1;
            int w1  = pcol[ni] + dw + 1;
            bbase[ni] = (row * WPITCH + w1) * 128;
            bsw[ni]   = w1 & 15;
        }
#pragma unroll
        for (int kc = 0; kc < 4; ++kc) {
            const int step = off * 4 + kc;
            if (step + 2 < 36) {
#pragma unroll
                for (int mi = 0; mi < 4; ++mi)
                    ap[(step + 2) % 3][mi] = *(const s16x8*)(arow[mi] + (step + 2) * 32);
            }
            const int jj = kc * 4 + quad;
            s16x8 bb[4];
#pragma unroll
            for (int ni = 0; ni < 4; ++ni)
                bb[ni] = *(const s16x8*)(xl + bbase[ni] + ((jj ^ bsw[ni]) << 3));
            const s16x8* a = ap[step % 3];
#pragma unroll
            for (int mi = 0; mi < 4; ++mi)
#pragma unroll
                for (int ni = 0; ni < 4; ++ni)
                    acc[mi][ni] = __builtin_amdgcn_mfma_f32_16x16x32_bf16(a[mi], bb[ni], acc[mi][ni], 0, 0, 0);
        }
    }

    __syncthreads();
    unsigned short* featb = xl;
#pragma unroll
    for (int mi = 0; mi < 4; ++mi)
#pragma unroll
        for (int ni = 0; ni < 4; ++ni) {
            int n = n_base + ni*16 + l16;
#pragma unroll
            for (int r = 0; r < 4; ++r) {
                int m = m_base + mi*16 + quad*4 + r;
                featb[m * 132 + n] = f2bf(acc[mi][ni][r]);
            }
        }
    __syncthreads();

    const size_t obase = ((size_t)b * OUTC) * 1024 + (size_t)nt * 128;
    for (int i = t; i < OUTC * 32; i += 256) {
        int pg = i & 31;
        int o  = i >> 5;
        int so = sel[o];
        float cc = cs[o];
        s16x4 fv = *(const s16x4*)(featb + so * 132 + pg * 4);
        f32x4 ov;
#pragma unroll
        for (int j = 0; j < 4; ++j)
            ov[j] = cc * bf2f((unsigned short)fv[j]);
        __builtin_nontemporal_store(ov, (f32x4*)(out + obase + (size_t)o * 1024 + pg * 4));
    }
}

extern "C" void kernel_launch(void* const* d_in, const int* in_sizes, int n_in,
                              void* d_out, int out_size, void* d_ws, size_t ws_size,
                              hipStream_t stream) {
    const float* x     = (const float*)d_in[0];
    const int*   label = (const int*)d_in[1];
    const float* ff    = (const float*)d_in[2];
    const float* coeff = (const float*)d_in[3];   // second_filter_coefficients (use [0] slice)
    const float* comb  = (const float*)d_in[4];   // second_filter_combination  (use [0] slice)
    float* out = (float*)d_out;

    char* ws = (char*)d_ws;
    unsigned short* wt  = (unsigned short*)ws;                  // 10*128*1152*2 = 2,949,120 B
    int*   sel = (int*)(ws + 2949120);                          // 2 KB
    float* cs  = (float*)(ws + 2949120 + 2048);                 // 2 KB
    unsigned short* xbf = (unsigned short*)(ws + 2949120 + 4096); // 128*34*4352*2 = 37,879,808 B

    const size_t need = 2949120ull + 4096ull + 37879808ull;     // 40,833,024 B

    k_prep_w  <<<640, 256, 0, stream>>>(ff, wt);
    k_prep_sel<<<2,   256, 0, stream>>>(coeff, comb, sel, cs);

    if (ws_size >= need) {
        k_prep_x <<<dim3(34, 128), 256, 0, stream>>>(x, xbf);
        k_conv_dma<<<dim3(8, 128), 256, 0, stream>>>(xbf, label, wt, sel, cs, out);
    } else {
        k_conv_old<<<dim3(8, 128), 256, 0, stream>>>(x, label, wt, sel, cs, out);
    }
}